// Round 1
// baseline (265.264 us; speedup 1.0000x reference)
//
#include <hip/hip_runtime.h>
#include <math.h>

#define N_CAT   1024
#define IN_DIM  4096
#define HID     4096
#define OUT_DIM 50257
#define XDIM    (N_CAT + IN_DIM)   // 5120 (GRU input width)
#define OCDIM   (N_CAT + HID)      // 5120 (output-proj input width)

// ws layout (floats): [0, 50304)  logits (padded to mult of 64)
//                     [50304, 54400) h_new aligned copy
#define WS_LOGITS 0
#define WS_HNEW   50304

__device__ __forceinline__ float dot4(float4 a, float4 b) {
    return a.x * b.x + a.y * b.y + a.z * b.z + a.w * b.w;
}

__device__ __forceinline__ float wave_reduce_sum(float v) {
    #pragma unroll
    for (int off = 32; off > 0; off >>= 1)
        v += __shfl_down(v, off, 64);
    return v;
}

// ---------------- Kernel A: GRU cell via 6 fused GEMV rows per block -------
// grid = HID blocks, 256 threads. Block j computes h_new[j].
__global__ __launch_bounds__(256) void gru_gemv(
    const float* __restrict__ cat,
    const float* __restrict__ inp,
    const float* __restrict__ hid,
    const float* __restrict__ w_ih,
    const float* __restrict__ b_ih,
    const float* __restrict__ w_hh,
    const float* __restrict__ b_hh,
    float* __restrict__ hnew_out,    // d_out + OUT_DIM (final output slot)
    float* __restrict__ hnew_ws)     // aligned ws copy for kernel B
{
    const int j    = blockIdx.x;
    const int tid  = threadIdx.x;
    const int lane = tid & 63;
    const int wave = tid >> 6;

    const float4* cat4 = (const float4*)cat;   // 256 float4
    const float4* in4  = (const float4*)inp;   // 1024 float4
    const float4* h4   = (const float4*)hid;   // 1024 float4
    const float4* wi4  = (const float4*)w_ih;
    const float4* wh4  = (const float4*)w_hh;

    float si[3] = {0.f, 0.f, 0.f};
    float sh[3] = {0.f, 0.f, 0.f};

    #pragma unroll
    for (int g = 0; g < 3; ++g) {
        const size_t row = (size_t)j + (size_t)g * HID;
        const float4* wrow = wi4 + row * (XDIM / 4);
        // category segment: 256 float4 -> exactly one per thread
        si[g] += dot4(wrow[tid], cat4[tid]);
        // input segment: 1024 float4
        #pragma unroll
        for (int k = 0; k < 4; ++k) {
            const int idx = tid + k * 256;
            si[g] += dot4(wrow[256 + idx], in4[idx]);
        }
        const float4* hrow = wh4 + row * (HID / 4);
        #pragma unroll
        for (int k = 0; k < 4; ++k) {
            const int idx = tid + k * 256;
            sh[g] += dot4(hrow[idx], h4[idx]);
        }
    }

    __shared__ float red[4][6];
    float vals[6] = {si[0], si[1], si[2], sh[0], sh[1], sh[2]};
    #pragma unroll
    for (int q = 0; q < 6; ++q) {
        const float r = wave_reduce_sum(vals[q]);
        if (lane == 0) red[wave][q] = r;
    }
    __syncthreads();

    if (tid == 0) {
        float t[6];
        #pragma unroll
        for (int q = 0; q < 6; ++q)
            t[q] = red[0][q] + red[1][q] + red[2][q] + red[3][q];
        const float gi_r = t[0] + b_ih[j];
        const float gi_z = t[1] + b_ih[j + HID];
        const float gi_n = t[2] + b_ih[j + 2 * HID];
        const float gh_r = t[3] + b_hh[j];
        const float gh_z = t[4] + b_hh[j + HID];
        const float gh_n = t[5] + b_hh[j + 2 * HID];

        const float r = 1.f / (1.f + expf(-(gi_r + gh_r)));
        const float z = 1.f / (1.f + expf(-(gi_z + gh_z)));
        const float n = tanhf(gi_n + r * gh_n);
        const float hn = (1.f - z) * n + z * hid[j];
        hnew_out[j] = hn;
        hnew_ws[j]  = hn;
    }
}

// ---------------- Kernel B: output projection, one wave per row ------------
// grid = ceil(OUT_DIM/4) blocks of 256 (4 waves); wave w does row 4*b+w.
__global__ __launch_bounds__(256) void out_gemv(
    const float* __restrict__ cat,
    const float* __restrict__ hnew,
    const float* __restrict__ w_out,
    const float* __restrict__ b_out,
    float* __restrict__ logits)
{
    const int lane = threadIdx.x & 63;
    const int wave = threadIdx.x >> 6;
    const int row  = blockIdx.x * 4 + wave;
    if (row >= OUT_DIM) return;

    const float4* cat4 = (const float4*)cat;                      // 256 f4
    const float4* h4   = (const float4*)hnew;                     // 1024 f4
    const float4* wrow = (const float4*)w_out + (size_t)row * (OCDIM / 4);

    float acc = 0.f;
    #pragma unroll
    for (int k = 0; k < 4; ++k) {
        const int idx = lane + k * 64;
        acc += dot4(wrow[idx], cat4[idx]);
    }
    #pragma unroll
    for (int k = 0; k < 16; ++k) {
        const int idx = lane + k * 64;
        acc += dot4(wrow[256 + idx], h4[idx]);
    }
    acc = wave_reduce_sum(acc);
    if (lane == 0) logits[row] = acc + b_out[row];
}

// ---------------- Kernel C: log_softmax over 50257, single block -----------
__global__ __launch_bounds__(1024) void logsoftmax(
    const float* __restrict__ logits,
    float* __restrict__ out)
{
    __shared__ float sred[16];
    __shared__ float sbcast;
    const int tid  = threadIdx.x;
    const int lane = tid & 63;
    const int wave = tid >> 6;

    // pass 1: max
    float lmax = -INFINITY;
    for (int i = tid; i < OUT_DIM; i += 1024)
        lmax = fmaxf(lmax, logits[i]);
    #pragma unroll
    for (int off = 32; off > 0; off >>= 1)
        lmax = fmaxf(lmax, __shfl_down(lmax, off, 64));
    if (lane == 0) sred[wave] = lmax;
    __syncthreads();
    if (tid == 0) {
        float m = sred[0];
        for (int w = 1; w < 16; ++w) m = fmaxf(m, sred[w]);
        sbcast = m;
    }
    __syncthreads();
    const float gmax = sbcast;

    // pass 2: sum of exp
    float lsum = 0.f;
    for (int i = tid; i < OUT_DIM; i += 1024)
        lsum += expf(logits[i] - gmax);
    lsum = wave_reduce_sum(lsum);
    if (lane == 0) sred[wave] = lsum;
    __syncthreads();
    if (tid == 0) {
        float s = 0.f;
        for (int w = 0; w < 16; ++w) s += sred[w];
        sbcast = gmax + logf(s);
    }
    __syncthreads();
    const float logZ = sbcast;

    // pass 3: write
    for (int i = tid; i < OUT_DIM; i += 1024)
        out[i] = logits[i] - logZ;
}

extern "C" void kernel_launch(void* const* d_in, const int* in_sizes, int n_in,
                              void* d_out, int out_size, void* d_ws, size_t ws_size,
                              hipStream_t stream) {
    (void)in_sizes; (void)n_in; (void)out_size; (void)ws_size;

    const float* cat   = (const float*)d_in[0];
    const float* inp   = (const float*)d_in[1];
    const float* hid   = (const float*)d_in[2];
    const float* w_ih  = (const float*)d_in[3];
    const float* b_ih  = (const float*)d_in[4];
    const float* w_hh  = (const float*)d_in[5];
    const float* b_hh  = (const float*)d_in[6];
    const float* w_out = (const float*)d_in[7];
    const float* b_out = (const float*)d_in[8];

    float* out    = (float*)d_out;          // [0,50257) logp, [50257,54353) h_new
    float* ws_f   = (float*)d_ws;
    float* logits = ws_f + WS_LOGITS;
    float* hnew   = ws_f + WS_HNEW;

    // A: GRU cell -> h_new
    gru_gemv<<<HID, 256, 0, stream>>>(cat, inp, hid, w_ih, b_ih, w_hh, b_hh,
                                      out + OUT_DIM, hnew);
    // B: logits = [cat, h_new] @ w_out^T + b_out
    out_gemv<<<(OUT_DIM + 3) / 4, 256, 0, stream>>>(cat, hnew, w_out, b_out, logits);
    // C: logp = log_softmax(logits)
    logsoftmax<<<1, 1024, 0, stream>>>(logits, out);
}

// Round 2
// 264.584 us; speedup vs baseline: 1.0026x; 1.0026x over previous
//
#include <hip/hip_runtime.h>
#include <math.h>

#define N_CAT   1024
#define IN_DIM  4096
#define HID     4096
#define OUT_DIM 50257
#define XDIM    (N_CAT + IN_DIM)   // 5120 (GRU input width)
#define OCDIM   (N_CAT + HID)      // 5120 (output-proj input width)
#define NB_OUT  ((OUT_DIM + 3) / 4)  // 12565 blocks in out_gemv

// ws layout (floats):
//   [0, 50304)        logits (padded)
//   [50304, 54400)    h_new aligned copy
//   [54400, 67008)    per-block max partials (12565, padded)
//   [67008, 79616)    per-block sumexp partials
//   [79616]           logZ
#define WS_LOGITS 0
#define WS_HNEW   50304
#define WS_PMAX   54400
#define WS_PSUM   67008
#define WS_LOGZ   79616

__device__ __forceinline__ float dot4(float4 a, float4 b) {
    return a.x * b.x + a.y * b.y + a.z * b.z + a.w * b.w;
}

__device__ __forceinline__ float wave_reduce_sum(float v) {
    #pragma unroll
    for (int off = 32; off > 0; off >>= 1)
        v += __shfl_down(v, off, 64);
    return v;
}

// ---------------- Kernel A: GRU cell via 6 fused GEMV rows per block -------
// grid = HID blocks, 256 threads. Block j computes h_new[j].
__global__ __launch_bounds__(256) void gru_gemv(
    const float* __restrict__ cat,
    const float* __restrict__ inp,
    const float* __restrict__ hid,
    const float* __restrict__ w_ih,
    const float* __restrict__ b_ih,
    const float* __restrict__ w_hh,
    const float* __restrict__ b_hh,
    float* __restrict__ hnew_out,    // d_out + OUT_DIM (final output slot)
    float* __restrict__ hnew_ws)     // aligned ws copy for kernel B
{
    const int j    = blockIdx.x;
    const int tid  = threadIdx.x;
    const int lane = tid & 63;
    const int wave = tid >> 6;

    const float4* cat4 = (const float4*)cat;   // 256 float4
    const float4* in4  = (const float4*)inp;   // 1024 float4
    const float4* h4   = (const float4*)hid;   // 1024 float4
    const float4* wi4  = (const float4*)w_ih;
    const float4* wh4  = (const float4*)w_hh;

    float si[3] = {0.f, 0.f, 0.f};
    float sh[3] = {0.f, 0.f, 0.f};

    #pragma unroll
    for (int g = 0; g < 3; ++g) {
        const size_t row = (size_t)j + (size_t)g * HID;
        const float4* wrow = wi4 + row * (XDIM / 4);
        // category segment: 256 float4 -> exactly one per thread
        si[g] += dot4(wrow[tid], cat4[tid]);
        // input segment: 1024 float4
        #pragma unroll
        for (int k = 0; k < 4; ++k) {
            const int idx = tid + k * 256;
            si[g] += dot4(wrow[256 + idx], in4[idx]);
        }
        const float4* hrow = wh4 + row * (HID / 4);
        #pragma unroll
        for (int k = 0; k < 4; ++k) {
            const int idx = tid + k * 256;
            sh[g] += dot4(hrow[idx], h4[idx]);
        }
    }

    __shared__ float red[4][6];
    float vals[6] = {si[0], si[1], si[2], sh[0], sh[1], sh[2]};
    #pragma unroll
    for (int q = 0; q < 6; ++q) {
        const float r = wave_reduce_sum(vals[q]);
        if (lane == 0) red[wave][q] = r;
    }
    __syncthreads();

    if (tid == 0) {
        float t[6];
        #pragma unroll
        for (int q = 0; q < 6; ++q)
            t[q] = red[0][q] + red[1][q] + red[2][q] + red[3][q];
        const float gi_r = t[0] + b_ih[j];
        const float gi_z = t[1] + b_ih[j + HID];
        const float gi_n = t[2] + b_ih[j + 2 * HID];
        const float gh_r = t[3] + b_hh[j];
        const float gh_z = t[4] + b_hh[j + HID];
        const float gh_n = t[5] + b_hh[j + 2 * HID];

        const float r = 1.f / (1.f + expf(-(gi_r + gh_r)));
        const float z = 1.f / (1.f + expf(-(gi_z + gh_z)));
        const float n = tanhf(gi_n + r * gh_n);
        const float hn = (1.f - z) * n + z * hid[j];
        hnew_out[j] = hn;
        hnew_ws[j]  = hn;
    }
}

// ---------------- Kernel B: output projection + per-block softmax partials -
// grid = NB_OUT blocks of 256 (4 waves); wave w does row 4*b+w.
// Each block also emits (max, sum_exp) over its 4 logits.
__global__ __launch_bounds__(256) void out_gemv(
    const float* __restrict__ cat,
    const float* __restrict__ hnew,
    const float* __restrict__ w_out,
    const float* __restrict__ b_out,
    float* __restrict__ logits,
    float* __restrict__ pmax,
    float* __restrict__ psum)
{
    const int lane  = threadIdx.x & 63;
    const int wave  = threadIdx.x >> 6;
    const int row   = blockIdx.x * 4 + wave;
    const bool valid = (row < OUT_DIM);

    float acc = 0.f;
    if (valid) {
        const float4* cat4 = (const float4*)cat;                      // 256 f4
        const float4* h4   = (const float4*)hnew;                     // 1024 f4
        const float4* wrow = (const float4*)w_out + (size_t)row * (OCDIM / 4);
        #pragma unroll
        for (int k = 0; k < 4; ++k) {
            const int idx = lane + k * 64;
            acc += dot4(wrow[idx], cat4[idx]);
        }
        #pragma unroll
        for (int k = 0; k < 16; ++k) {
            const int idx = lane + k * 64;
            acc += dot4(wrow[256 + idx], h4[idx]);
        }
    }
    acc = wave_reduce_sum(acc);

    __shared__ float svals[4];
    if (lane == 0)
        svals[wave] = valid ? (acc + b_out[row]) : -INFINITY;
    __syncthreads();

    if (threadIdx.x == 0) {
        const float v0 = svals[0], v1 = svals[1], v2 = svals[2], v3 = svals[3];
        const float m = fmaxf(fmaxf(v0, v1), fmaxf(v2, v3));
        // exp(-inf - m) == 0, so invalid rows contribute nothing
        const float s = expf(v0 - m) + expf(v1 - m) + expf(v2 - m) + expf(v3 - m);
        pmax[blockIdx.x] = m;
        psum[blockIdx.x] = s;
    }
    if (lane == 0 && valid)
        logits[row] = svals[wave];
}

// ---------------- Kernel C2: combine 12565 (max,sum) pairs -> logZ ---------
__global__ __launch_bounds__(1024) void softmax_combine(
    const float* __restrict__ pmax,
    const float* __restrict__ psum,
    float* __restrict__ logz)
{
    __shared__ float sred[16];
    __shared__ float sb;
    const int tid  = threadIdx.x;
    const int lane = tid & 63;
    const int wave = tid >> 6;

    float m = -INFINITY;
    for (int i = tid; i < NB_OUT; i += 1024)
        m = fmaxf(m, pmax[i]);
    #pragma unroll
    for (int off = 32; off > 0; off >>= 1)
        m = fmaxf(m, __shfl_down(m, off, 64));
    if (lane == 0) sred[wave] = m;
    __syncthreads();
    if (tid == 0) {
        float mm = sred[0];
        for (int w = 1; w < 16; ++w) mm = fmaxf(mm, sred[w]);
        sb = mm;
    }
    __syncthreads();
    const float M = sb;

    float s = 0.f;
    for (int i = tid; i < NB_OUT; i += 1024)
        s += psum[i] * expf(pmax[i] - M);
    s = wave_reduce_sum(s);
    if (lane == 0) sred[wave] = s;
    __syncthreads();
    if (tid == 0) {
        float ss = 0.f;
        for (int w = 0; w < 16; ++w) ss += sred[w];
        *logz = M + logf(ss);
    }
}

// ---------------- Kernel C3: out = logits - logZ (vectorized) --------------
// 12564 full float4 groups + 1 tail element. grid = 50 blocks of 256.
__global__ __launch_bounds__(256) void write_logp(
    const float* __restrict__ logits,
    const float* __restrict__ logz,
    float* __restrict__ out)
{
    const float lz = *logz;
    const int t = blockIdx.x * 256 + threadIdx.x;
    const int n4 = OUT_DIM / 4;   // 12564
    if (t < n4) {
        float4 v = ((const float4*)logits)[t];
        v.x -= lz; v.y -= lz; v.z -= lz; v.w -= lz;
        ((float4*)out)[t] = v;
    } else if (t == n4) {
        out[OUT_DIM - 1] = logits[OUT_DIM - 1] - lz;
    }
}

extern "C" void kernel_launch(void* const* d_in, const int* in_sizes, int n_in,
                              void* d_out, int out_size, void* d_ws, size_t ws_size,
                              hipStream_t stream) {
    (void)in_sizes; (void)n_in; (void)out_size; (void)ws_size;

    const float* cat   = (const float*)d_in[0];
    const float* inp   = (const float*)d_in[1];
    const float* hid   = (const float*)d_in[2];
    const float* w_ih  = (const float*)d_in[3];
    const float* b_ih  = (const float*)d_in[4];
    const float* w_hh  = (const float*)d_in[5];
    const float* b_hh  = (const float*)d_in[6];
    const float* w_out = (const float*)d_in[7];
    const float* b_out = (const float*)d_in[8];

    float* out    = (float*)d_out;          // [0,50257) logp, [50257,54353) h_new
    float* ws_f   = (float*)d_ws;
    float* logits = ws_f + WS_LOGITS;
    float* hnew   = ws_f + WS_HNEW;
    float* pmax   = ws_f + WS_PMAX;
    float* psum   = ws_f + WS_PSUM;
    float* logz   = ws_f + WS_LOGZ;

    // A: GRU cell -> h_new
    gru_gemv<<<HID, 256, 0, stream>>>(cat, inp, hid, w_ih, b_ih, w_hh, b_hh,
                                      out + OUT_DIM, hnew);
    // B: logits = [cat, h_new] @ w_out^T + b_out, plus per-block (max,sumexp)
    out_gemv<<<NB_OUT, 256, 0, stream>>>(cat, hnew, w_out, b_out,
                                         logits, pmax, psum);
    // C2: logZ from partials
    softmax_combine<<<1, 1024, 0, stream>>>(pmax, psum, logz);
    // C3: logp = logits - logZ
    write_logp<<<(NB_OUT + 255) / 256, 256, 0, stream>>>(logits, logz, out);
}